// Round 1
// baseline (468.311 us; speedup 1.0000x reference)
//
#include <hip/hip_runtime.h>

#define S_LEN 2048
#define B_SZ 2
#define DMODEL 2048
#define NHEADS 16
#define NKV 4
#define DHEAD 128
#define SCALE 0.08838834764831845f  // 1/sqrt(128)

typedef __bf16 bf16x8 __attribute__((ext_vector_type(8)));
typedef __bf16 bf16x4 __attribute__((ext_vector_type(4)));
typedef float f32x4 __attribute__((ext_vector_type(4)));

#define MFMA(a, b, c) __builtin_amdgcn_mfma_f32_16x16x32_bf16(a, b, c, 0, 0, 0)

// ---------------------------------------------------------------------------
// RoPE tables: cos/sin [S][64]
// ---------------------------------------------------------------------------
__global__ void rope_tables_kernel(float* __restrict__ cosT, float* __restrict__ sinT) {
    int i = blockIdx.x * 256 + threadIdx.x;       // S*64 entries
    int s = i >> 6, d = i & 63;
    float freq = powf(10000.0f, -(2.0f * (float)d) / 128.0f);
    float ang = (float)s * freq;
    cosT[i] = cosf(ang);
    sinT[i] = sinf(ang);
}

// ---------------------------------------------------------------------------
// GEMM: C[m][n] = sum_k A[m][k] * W[n][k]   (W is [N][K] row-major = B^T)
// 128x128 tile, BK=32, 256 threads = 4 waves (2x2 of 64x64), 16x16x32 bf16 MFMA
// ---------------------------------------------------------------------------
template <bool ABF16>
__device__ __forceinline__ void gemm_bt_body(const void* __restrict__ Av,
                                             const float* __restrict__ W,
                                             float* __restrict__ C, int ldc,
                                             int bm, int bn, int K) {
    __shared__ alignas(16) __bf16 As[128][32];
    __shared__ alignas(16) __bf16 Bs[128][32];
    const int tid = threadIdx.x;
    const int lane = tid & 63;
    const int wave = tid >> 6;
    const int lr = lane & 15;        // row-in-16 for A/B frags, col for C
    const int lk = lane >> 4;        // k-chunk id 0..3, row-group for C
    const int wm = (wave >> 1) * 64;
    const int wn = (wave & 1) * 64;

    f32x4 acc[4][4] = {};

    for (int k0 = 0; k0 < K; k0 += 32) {
        __syncthreads();  // prior-iter LDS reads done before overwrite
        if constexpr (ABF16) {
            const __bf16* A = (const __bf16*)Av;
#pragma unroll
            for (int i = 0; i < 2; ++i) {
                int idx = tid + i * 256;          // 512 chunks of 8 bf16
                int row = idx >> 2, c8 = idx & 3;
                *(bf16x8*)&As[row][c8 * 8] =
                    *(const bf16x8*)&A[(size_t)(bm + row) * K + k0 + c8 * 8];
            }
        } else {
            const float* A = (const float*)Av;
#pragma unroll
            for (int i = 0; i < 4; ++i) {
                int idx = tid + i * 256;          // 1024 chunks of 4 floats
                int row = idx >> 3, c4 = idx & 7;
                float4 v = *(const float4*)&A[(size_t)(bm + row) * K + k0 + c4 * 4];
                bf16x4 bv = {(__bf16)v.x, (__bf16)v.y, (__bf16)v.z, (__bf16)v.w};
                *(bf16x4*)&As[row][c4 * 4] = bv;
            }
        }
#pragma unroll
        for (int i = 0; i < 4; ++i) {
            int idx = tid + i * 256;
            int row = idx >> 3, c4 = idx & 7;
            float4 v = *(const float4*)&W[(size_t)(bn + row) * K + k0 + c4 * 4];
            bf16x4 bv = {(__bf16)v.x, (__bf16)v.y, (__bf16)v.z, (__bf16)v.w};
            *(bf16x4*)&Bs[row][c4 * 4] = bv;
        }
        __syncthreads();

        bf16x8 af[4], bfr[4];
#pragma unroll
        for (int i = 0; i < 4; ++i) {
            af[i]  = *(const bf16x8*)&As[wm + i * 16 + lr][lk * 8];
            bfr[i] = *(const bf16x8*)&Bs[wn + i * 16 + lr][lk * 8];
        }
#pragma unroll
        for (int mi = 0; mi < 4; ++mi)
#pragma unroll
            for (int ni = 0; ni < 4; ++ni)
                acc[mi][ni] = MFMA(af[mi], bfr[ni], acc[mi][ni]);
    }

#pragma unroll
    for (int mi = 0; mi < 4; ++mi)
#pragma unroll
        for (int ni = 0; ni < 4; ++ni)
#pragma unroll
            for (int r = 0; r < 4; ++r) {
                int row = bm + wm + mi * 16 + lk * 4 + r;
                int col = bn + wn + ni * 16 + lr;
                C[(size_t)row * ldc + col] = acc[mi][ni][r];
            }
}

// grid (M/128, 24): ny 0..15 -> Q, 16..19 -> K, 20..23 -> V
__global__ __launch_bounds__(256) void qkv_proj_kernel(
    const float* __restrict__ qkv, const float* __restrict__ Wq,
    const float* __restrict__ Wk, const float* __restrict__ Wv,
    float* __restrict__ q_tmp, float* __restrict__ k_tmp, float* __restrict__ v_tmp) {
    int bm = blockIdx.x * 128;
    int ny = blockIdx.y;
    const float* W;
    float* C;
    int ldc, bn;
    if (ny < 16)      { W = Wq; C = q_tmp; ldc = 2048; bn = ny * 128; }
    else if (ny < 20) { W = Wk; C = k_tmp; ldc = 512;  bn = (ny - 16) * 128; }
    else              { W = Wv; C = v_tmp; ldc = 512;  bn = (ny - 20) * 128; }
    gemm_bt_body<false>(qkv, W, C, ldc, bm, bn, 2048);
}

__global__ __launch_bounds__(256) void out_proj_kernel(
    const __bf16* __restrict__ att, const float* __restrict__ Wo,
    float* __restrict__ out) {
    gemm_bt_body<true>(att, Wo, out, 2048, blockIdx.x * 128, blockIdx.y * 128, 2048);
}

// ---------------------------------------------------------------------------
// RMSNorm + RoPE + bf16 + transpose for Q,K.  grid (B*S), 256 threads.
// qb: [B,H,S,Dh]  kb: [B,KV,S,Dh]
// ---------------------------------------------------------------------------
__global__ __launch_bounds__(256) void postproc_kernel(
    const float* __restrict__ q_tmp, const float* __restrict__ k_tmp,
    const float* __restrict__ qg, const float* __restrict__ kg,
    const float* __restrict__ cosT, const float* __restrict__ sinT,
    __bf16* __restrict__ qb, __bf16* __restrict__ kb) {
    int bs = blockIdx.x;
    int b = bs >> 11, s = bs & 2047;
    int wave = threadIdx.x >> 6, lane = threadIdx.x & 63;
    float c  = cosT[s * 64 + lane];
    float sn = sinT[s * 64 + lane];
    float g1q = qg[lane], g2q = qg[lane + 64];
    float g1k = kg[lane], g2k = kg[lane + 64];

    for (int h = wave; h < NHEADS; h += 4) {
        const float* row = q_tmp + (size_t)bs * 2048 + h * 128;
        float x1 = row[lane], x2 = row[lane + 64];
        float ss = x1 * x1 + x2 * x2;
#pragma unroll
        for (int m = 1; m < 64; m <<= 1) ss += __shfl_xor(ss, m);
        float rs = rsqrtf(ss * (1.0f / 128.0f) + 1e-6f);
        float n1 = x1 * rs * g1q, n2 = x2 * rs * g2q;
        float y1 = n1 * c - n2 * sn;
        float y2 = n2 * c + n1 * sn;
        __bf16* orow = qb + (((size_t)(b * NHEADS + h)) * S_LEN + s) * DHEAD;
        orow[lane] = (__bf16)y1;
        orow[lane + 64] = (__bf16)y2;
    }
    int h = wave;
    if (h < NKV) {
        const float* row = k_tmp + (size_t)bs * 512 + h * 128;
        float x1 = row[lane], x2 = row[lane + 64];
        float ss = x1 * x1 + x2 * x2;
#pragma unroll
        for (int m = 1; m < 64; m <<= 1) ss += __shfl_xor(ss, m);
        float rs = rsqrtf(ss * (1.0f / 128.0f) + 1e-6f);
        float n1 = x1 * rs * g1k, n2 = x2 * rs * g2k;
        float y1 = n1 * c - n2 * sn;
        float y2 = n2 * c + n1 * sn;
        __bf16* orow = kb + (((size_t)(b * NKV + h)) * S_LEN + s) * DHEAD;
        orow[lane] = (__bf16)y1;
        orow[lane + 64] = (__bf16)y2;
    }
}

// ---------------------------------------------------------------------------
// V transpose: v_tmp fp32 [B*S][512] -> vt bf16 [B,KV,Dh,S]
// grid (B*KV, S/64, Dh/64), 256 threads, 64x64 LDS tile (+1 pad)
// ---------------------------------------------------------------------------
__global__ __launch_bounds__(256) void v_transpose_kernel(
    const float* __restrict__ v_tmp, __bf16* __restrict__ vt) {
    int bkv = blockIdx.x;
    int b = bkv >> 2, kvh = bkv & 3;
    int s0 = blockIdx.y * 64, d0 = blockIdx.z * 64;
    __shared__ float tile[64][65];
#pragma unroll
    for (int i = 0; i < 16; ++i) {
        int idx = threadIdx.x + i * 256;
        int r = idx >> 6, cc = idx & 63;
        tile[r][cc] = v_tmp[((size_t)(b * S_LEN) + s0 + r) * 512 + kvh * 128 + d0 + cc];
    }
    __syncthreads();
#pragma unroll
    for (int i = 0; i < 16; ++i) {
        int idx = threadIdx.x + i * 256;
        int r = idx >> 6, cc = idx & 63;   // r = d-local, cc = s-local
        vt[((size_t)bkv * DHEAD + d0 + r) * S_LEN + s0 + cc] = (__bf16)tile[cc][r];
    }
}

// ---------------------------------------------------------------------------
// Causal flash attention.  grid (B*H, S/64), 256 threads = 4 waves.
// Wave w handles q rows [q0+16w, q0+16w+16), loops its own kv-tile count.
// qb [B,H,S,Dh], kb [B,KV,S,Dh], vt [B,KV,Dh,S] -> att bf16 [B,S,H*Dh]
// ---------------------------------------------------------------------------
__global__ __launch_bounds__(256) void flash_kernel(
    const __bf16* __restrict__ qb, const __bf16* __restrict__ kb,
    const __bf16* __restrict__ vt, __bf16* __restrict__ att) {
    __shared__ alignas(16) __bf16 p_lds[4][16][32];
    const int bh = blockIdx.x;
    const int b = bh >> 4, h = bh & 15, kv = h >> 2;
    const int q0 = blockIdx.y * 64;
    const int lane = threadIdx.x & 63, wave = threadIdx.x >> 6;
    const int lr = lane & 15, lk = lane >> 4;
    const int qbase = q0 + wave * 16;

    const __bf16* Qp = qb + ((size_t)(b * NHEADS + h)) * S_LEN * DHEAD;
    const __bf16* Kp = kb + ((size_t)(b * NKV + kv)) * S_LEN * DHEAD;
    const __bf16* Vt = vt + ((size_t)(b * NKV + kv)) * DHEAD * S_LEN;

    bf16x8 qf[4];
#pragma unroll
    for (int f = 0; f < 4; ++f)
        qf[f] = *(const bf16x8*)&Qp[(size_t)(qbase + lr) * DHEAD + f * 32 + lk * 8];

    f32x4 acc[8] = {};
    float mrow[4] = {-1e30f, -1e30f, -1e30f, -1e30f};
    float lsum[4] = {0.f, 0.f, 0.f, 0.f};

    const int nt = ((qbase + 15) >> 5) + 1;  // kv tiles of 32
    for (int t = 0; t < nt; ++t) {
        const int k0 = t * 32;
        // ---- S = Q K^T for 32 keys (2 x 16-col tiles)
        f32x4 sc[2] = {};
#pragma unroll
        for (int kk = 0; kk < 2; ++kk)
#pragma unroll
            for (int f = 0; f < 4; ++f) {
                bf16x8 kf = *(const bf16x8*)&Kp[(size_t)(k0 + kk * 16 + lr) * DHEAD + f * 32 + lk * 8];
                sc[kk] = MFMA(qf[f], kf, sc[kk]);
            }
        // ---- scale + causal mask + row max (reduce over 16 lanes = key cols)
        float mt[4];
#pragma unroll
        for (int r = 0; r < 4; ++r) {
            const int qr = qbase + lk * 4 + r;
            float s0 = sc[0][r] * SCALE;
            float s1 = sc[1][r] * SCALE;
            if (k0 + lr > qr) s0 = -1e30f;
            if (k0 + 16 + lr > qr) s1 = -1e30f;
            sc[0][r] = s0;
            sc[1][r] = s1;
            float mx = fmaxf(s0, s1);
            mx = fmaxf(mx, __shfl_xor(mx, 1));
            mx = fmaxf(mx, __shfl_xor(mx, 2));
            mx = fmaxf(mx, __shfl_xor(mx, 4));
            mx = fmaxf(mx, __shfl_xor(mx, 8));
            mt[r] = mx;
        }
        // prior-iter P reads must be done before overwriting (per-wave buffer,
        // so a wave-level waitcnt is sufficient — no __syncthreads)
        asm volatile("s_waitcnt lgkmcnt(0)" ::: "memory");
        // ---- online softmax update + stash P into per-wave LDS (transpose)
#pragma unroll
        for (int r = 0; r < 4; ++r) {
            float newm = fmaxf(mrow[r], mt[r]);
            float alpha = __expf(mrow[r] - newm);
            float p0 = __expf(sc[0][r] - newm);
            float p1 = __expf(sc[1][r] - newm);
            float rs = p0 + p1;
            rs += __shfl_xor(rs, 1);
            rs += __shfl_xor(rs, 2);
            rs += __shfl_xor(rs, 4);
            rs += __shfl_xor(rs, 8);
            lsum[r] = lsum[r] * alpha + rs;
            mrow[r] = newm;
#pragma unroll
            for (int nf = 0; nf < 8; ++nf) acc[nf][r] *= alpha;
            p_lds[wave][lk * 4 + r][lr] = (__bf16)p0;
            p_lds[wave][lk * 4 + r][16 + lr] = (__bf16)p1;
        }
        asm volatile("s_waitcnt lgkmcnt(0)" ::: "memory");
        // ---- PV: attended += P(16x32) * V(32x128)
        bf16x8 pf = *(const bf16x8*)&p_lds[wave][lr][lk * 8];
#pragma unroll
        for (int nf = 0; nf < 8; ++nf) {
            bf16x8 vf = *(const bf16x8*)&Vt[(size_t)(nf * 16 + lr) * S_LEN + k0 + lk * 8];
            acc[nf] = MFMA(pf, vf, acc[nf]);
        }
    }
    // ---- normalize + store (att row-major [B*S][2048])
#pragma unroll
    for (int nf = 0; nf < 8; ++nf)
#pragma unroll
        for (int r = 0; r < 4; ++r) {
            int qr = qbase + lk * 4 + r;
            float o = acc[nf][r] / lsum[r];
            att[((size_t)(b * S_LEN) + qr) * DMODEL + h * DHEAD + nf * 16 + lr] = (__bf16)o;
        }
}

// ---------------------------------------------------------------------------
extern "C" void kernel_launch(void* const* d_in, const int* in_sizes, int n_in,
                              void* d_out, int out_size, void* d_ws, size_t ws_size,
                              hipStream_t stream) {
    const float* qkv = (const float*)d_in[0];
    const float* Wq  = (const float*)d_in[1];
    const float* Wk  = (const float*)d_in[2];
    const float* Wv  = (const float*)d_in[3];
    const float* Wo  = (const float*)d_in[4];
    const float* qg  = (const float*)d_in[5];
    const float* kg  = (const float*)d_in[6];
    float* out = (float*)d_out;

    size_t off = 0;
    char* wsb = (char*)d_ws;
    auto alloc = [&](size_t n) {
        char* p = wsb + off;
        off += (n + 255) & ~(size_t)255;
        return (void*)p;
    };
    const size_t M = (size_t)B_SZ * S_LEN;  // 4096
    float* cosT  = (float*)alloc((size_t)S_LEN * 64 * 4);
    float* sinT  = (float*)alloc((size_t)S_LEN * 64 * 4);
    float* q_tmp = (float*)alloc(M * 2048 * 4);
    float* k_tmp = (float*)alloc(M * 512 * 4);
    float* v_tmp = (float*)alloc(M * 512 * 4);
    __bf16* qb   = (__bf16*)alloc((size_t)B_SZ * NHEADS * S_LEN * DHEAD * 2);
    __bf16* kb   = (__bf16*)alloc((size_t)B_SZ * NKV * S_LEN * DHEAD * 2);
    __bf16* vt   = (__bf16*)alloc((size_t)B_SZ * NKV * DHEAD * S_LEN * 2);
    __bf16* att  = (__bf16*)alloc(M * DMODEL * 2);

    rope_tables_kernel<<<(S_LEN * 64) / 256, 256, 0, stream>>>(cosT, sinT);
    qkv_proj_kernel<<<dim3(M / 128, 24), 256, 0, stream>>>(qkv, Wq, Wk, Wv,
                                                           q_tmp, k_tmp, v_tmp);
    postproc_kernel<<<dim3(M), 256, 0, stream>>>(q_tmp, k_tmp, qg, kg, cosT, sinT, qb, kb);
    v_transpose_kernel<<<dim3(B_SZ * NKV, S_LEN / 64, DHEAD / 64), 256, 0, stream>>>(v_tmp, vt);
    flash_kernel<<<dim3(B_SZ * NHEADS, S_LEN / 64), 256, 0, stream>>>(qb, kb, vt, att);
    out_proj_kernel<<<dim3(M / 128, DMODEL / 128), 256, 0, stream>>>(att, Wo, out);
}

// Round 2
// 416.058 us; speedup vs baseline: 1.1256x; 1.1256x over previous
//
#include <hip/hip_runtime.h>

#define S_LEN 2048
#define B_SZ 2
#define DMODEL 2048
#define NHEADS 16
#define NKV 4
#define DHEAD 128
#define SCALE 0.08838834764831845f  // 1/sqrt(128)

typedef __bf16 bf16x8 __attribute__((ext_vector_type(8)));
typedef __bf16 bf16x4 __attribute__((ext_vector_type(4)));
typedef float f32x4 __attribute__((ext_vector_type(4)));

#define MFMA(a, b, c) __builtin_amdgcn_mfma_f32_16x16x32_bf16(a, b, c, 0, 0, 0)

// ---------------------------------------------------------------------------
// RoPE tables: cos/sin [S][64]
// ---------------------------------------------------------------------------
__global__ void rope_tables_kernel(float* __restrict__ cosT, float* __restrict__ sinT) {
    int i = blockIdx.x * 256 + threadIdx.x;       // S*64 entries
    int s = i >> 6, d = i & 63;
    float freq = powf(10000.0f, -(2.0f * (float)d) / 128.0f);
    float ang = (float)s * freq;
    cosT[i] = cosf(ang);
    sinT[i] = sinf(ang);
}

// ---------------------------------------------------------------------------
// GEMM: C[m][n] = sum_k A[m][k] * W[n][k]   (W is [N][K] row-major = B^T)
// 128x128 tile, BK=32, 256 threads = 4 waves (2x2 of 64x64), 16x16x32 bf16 MFMA
// ---------------------------------------------------------------------------
template <bool ABF16>
__device__ __forceinline__ void gemm_bt_body(const void* __restrict__ Av,
                                             const float* __restrict__ W,
                                             float* __restrict__ C, int ldc,
                                             int bm, int bn, int K) {
    __shared__ alignas(16) __bf16 As[128][32];
    __shared__ alignas(16) __bf16 Bs[128][32];
    const int tid = threadIdx.x;
    const int lane = tid & 63;
    const int wave = tid >> 6;
    const int lr = lane & 15;        // row-in-16 for A/B frags, col for C
    const int lk = lane >> 4;        // k-chunk id 0..3, row-group for C
    const int wm = (wave >> 1) * 64;
    const int wn = (wave & 1) * 64;

    f32x4 acc[4][4] = {};

    for (int k0 = 0; k0 < K; k0 += 32) {
        __syncthreads();  // prior-iter LDS reads done before overwrite
        if constexpr (ABF16) {
            const __bf16* A = (const __bf16*)Av;
#pragma unroll
            for (int i = 0; i < 2; ++i) {
                int idx = tid + i * 256;          // 512 chunks of 8 bf16
                int row = idx >> 2, c8 = idx & 3;
                *(bf16x8*)&As[row][c8 * 8] =
                    *(const bf16x8*)&A[(size_t)(bm + row) * K + k0 + c8 * 8];
            }
        } else {
            const float* A = (const float*)Av;
#pragma unroll
            for (int i = 0; i < 4; ++i) {
                int idx = tid + i * 256;          // 1024 chunks of 4 floats
                int row = idx >> 3, c4 = idx & 7;
                float4 v = *(const float4*)&A[(size_t)(bm + row) * K + k0 + c4 * 4];
                bf16x4 bv = {(__bf16)v.x, (__bf16)v.y, (__bf16)v.z, (__bf16)v.w};
                *(bf16x4*)&As[row][c4 * 4] = bv;
            }
        }
#pragma unroll
        for (int i = 0; i < 4; ++i) {
            int idx = tid + i * 256;
            int row = idx >> 3, c4 = idx & 7;
            float4 v = *(const float4*)&W[(size_t)(bn + row) * K + k0 + c4 * 4];
            bf16x4 bv = {(__bf16)v.x, (__bf16)v.y, (__bf16)v.z, (__bf16)v.w};
            *(bf16x4*)&Bs[row][c4 * 4] = bv;
        }
        __syncthreads();

        bf16x8 af[4], bfr[4];
#pragma unroll
        for (int i = 0; i < 4; ++i) {
            af[i]  = *(const bf16x8*)&As[wm + i * 16 + lr][lk * 8];
            bfr[i] = *(const bf16x8*)&Bs[wn + i * 16 + lr][lk * 8];
        }
#pragma unroll
        for (int mi = 0; mi < 4; ++mi)
#pragma unroll
            for (int ni = 0; ni < 4; ++ni)
                acc[mi][ni] = MFMA(af[mi], bfr[ni], acc[mi][ni]);
    }

#pragma unroll
    for (int mi = 0; mi < 4; ++mi)
#pragma unroll
        for (int ni = 0; ni < 4; ++ni)
#pragma unroll
            for (int r = 0; r < 4; ++r) {
                int row = bm + wm + mi * 16 + lk * 4 + r;
                int col = bn + wn + ni * 16 + lr;
                C[(size_t)row * ldc + col] = acc[mi][ni][r];
            }
}

// grid (M/128, 24): ny 0..15 -> Q, 16..19 -> K, 20..23 -> V
__global__ __launch_bounds__(256) void qkv_proj_kernel(
    const float* __restrict__ qkv, const float* __restrict__ Wq,
    const float* __restrict__ Wk, const float* __restrict__ Wv,
    float* __restrict__ q_tmp, float* __restrict__ k_tmp, float* __restrict__ v_tmp) {
    int bm = blockIdx.x * 128;
    int ny = blockIdx.y;
    const float* W;
    float* C;
    int ldc, bn;
    if (ny < 16)      { W = Wq; C = q_tmp; ldc = 2048; bn = ny * 128; }
    else if (ny < 20) { W = Wk; C = k_tmp; ldc = 512;  bn = (ny - 16) * 128; }
    else              { W = Wv; C = v_tmp; ldc = 512;  bn = (ny - 20) * 128; }
    gemm_bt_body<false>(qkv, W, C, ldc, bm, bn, 2048);
}

__global__ __launch_bounds__(256) void out_proj_kernel(
    const __bf16* __restrict__ att, const float* __restrict__ Wo,
    float* __restrict__ out) {
    gemm_bt_body<true>(att, Wo, out, 2048, blockIdx.x * 128, blockIdx.y * 128, 2048);
}

// ---------------------------------------------------------------------------
// RMSNorm + RoPE + bf16 + transpose for Q,K.  grid (B*S), 256 threads.
// qb: [B,H,S,Dh] (pre-scaled by 1/sqrt(Dh))  kb: [B,KV,S,Dh]
// ---------------------------------------------------------------------------
__global__ __launch_bounds__(256) void postproc_kernel(
    const float* __restrict__ q_tmp, const float* __restrict__ k_tmp,
    const float* __restrict__ qg, const float* __restrict__ kg,
    const float* __restrict__ cosT, const float* __restrict__ sinT,
    __bf16* __restrict__ qb, __bf16* __restrict__ kb) {
    int bs = blockIdx.x;
    int b = bs >> 11, s = bs & 2047;
    int wave = threadIdx.x >> 6, lane = threadIdx.x & 63;
    float c  = cosT[s * 64 + lane];
    float sn = sinT[s * 64 + lane];
    float g1q = qg[lane], g2q = qg[lane + 64];
    float g1k = kg[lane], g2k = kg[lane + 64];

    for (int h = wave; h < NHEADS; h += 4) {
        const float* row = q_tmp + (size_t)bs * 2048 + h * 128;
        float x1 = row[lane], x2 = row[lane + 64];
        float ss = x1 * x1 + x2 * x2;
#pragma unroll
        for (int m = 1; m < 64; m <<= 1) ss += __shfl_xor(ss, m);
        float rs = rsqrtf(ss * (1.0f / 128.0f) + 1e-6f);
        float n1 = x1 * rs * g1q, n2 = x2 * rs * g2q;
        // fold the attention score scale into q
        float y1 = (n1 * c - n2 * sn) * SCALE;
        float y2 = (n2 * c + n1 * sn) * SCALE;
        __bf16* orow = qb + (((size_t)(b * NHEADS + h)) * S_LEN + s) * DHEAD;
        orow[lane] = (__bf16)y1;
        orow[lane + 64] = (__bf16)y2;
    }
    int h = wave;
    if (h < NKV) {
        const float* row = k_tmp + (size_t)bs * 512 + h * 128;
        float x1 = row[lane], x2 = row[lane + 64];
        float ss = x1 * x1 + x2 * x2;
#pragma unroll
        for (int m = 1; m < 64; m <<= 1) ss += __shfl_xor(ss, m);
        float rs = rsqrtf(ss * (1.0f / 128.0f) + 1e-6f);
        float n1 = x1 * rs * g1k, n2 = x2 * rs * g2k;
        float y1 = n1 * c - n2 * sn;
        float y2 = n2 * c + n1 * sn;
        __bf16* orow = kb + (((size_t)(b * NKV + h)) * S_LEN + s) * DHEAD;
        orow[lane] = (__bf16)y1;
        orow[lane + 64] = (__bf16)y2;
    }
}

// ---------------------------------------------------------------------------
// V transpose: v_tmp fp32 [B*S][512] -> vt bf16 [B,KV,Dh,S]
// ---------------------------------------------------------------------------
__global__ __launch_bounds__(256) void v_transpose_kernel(
    const float* __restrict__ v_tmp, __bf16* __restrict__ vt) {
    int bkv = blockIdx.x;
    int b = bkv >> 2, kvh = bkv & 3;
    int s0 = blockIdx.y * 64, d0 = blockIdx.z * 64;
    __shared__ float tile[64][65];
#pragma unroll
    for (int i = 0; i < 16; ++i) {
        int idx = threadIdx.x + i * 256;
        int r = idx >> 6, cc = idx & 63;
        tile[r][cc] = v_tmp[((size_t)(b * S_LEN) + s0 + r) * 512 + kvh * 128 + d0 + cc];
    }
    __syncthreads();
#pragma unroll
    for (int i = 0; i < 16; ++i) {
        int idx = threadIdx.x + i * 256;
        int r = idx >> 6, cc = idx & 63;   // r = d-local, cc = s-local
        vt[((size_t)bkv * DHEAD + d0 + r) * S_LEN + s0 + cc] = (__bf16)tile[cc][r];
    }
}

// ---------------------------------------------------------------------------
// Causal flash attention, pair-balanced, max-free softmax.
// grid (B*H, 32), 256 threads = 4 waves.
// Half-tiles of 32 rows: waves 0,1 -> half-tile j; waves 2,3 -> half-tile 63-j.
// Every block does exactly 130 KV tiles (perfect balance).
// qb [B,H,S,Dh] (q pre-scaled), kb [B,KV,S,Dh], vt [B,KV,Dh,S] -> att [B,S,H*Dh]
// ---------------------------------------------------------------------------
__global__ __launch_bounds__(256) void flash_kernel(
    const __bf16* __restrict__ qb, const __bf16* __restrict__ kb,
    const __bf16* __restrict__ vt, __bf16* __restrict__ att) {
    __shared__ alignas(16) __bf16 p_lds[4][16][40];  // 80B row stride: ~2-way banks
    const int bh = blockIdx.x;
    const int b = bh >> 4, h = bh & 15, kv = h >> 2;
    const int lane = threadIdx.x & 63, wave = threadIdx.x >> 6;
    const int lr = lane & 15, lk = lane >> 4;
    const int j = blockIdx.y;                 // 0..31
    const int j32 = (wave < 2) ? j : (63 - j);
    const int qbase = j32 * 32 + (wave & 1) * 16;

    const __bf16* Qp = qb + ((size_t)(b * NHEADS + h)) * S_LEN * DHEAD;
    const __bf16* Kp = kb + ((size_t)(b * NKV + kv)) * S_LEN * DHEAD;
    const __bf16* Vt = vt + ((size_t)(b * NKV + kv)) * DHEAD * S_LEN;

    bf16x8 qf[4];
#pragma unroll
    for (int f = 0; f < 4; ++f)
        qf[f] = *(const bf16x8*)&Qp[(size_t)(qbase + lr) * DHEAD + f * 32 + lk * 8];

    f32x4 acc[8] = {};
    float lsum[4] = {0.f, 0.f, 0.f, 0.f};

    const int nt = (qbase >> 5) + 1;  // kv tiles of 32
    for (int t = 0; t < nt; ++t) {
        const int k0 = t * 32;
        // ---- issue all K and V loads for this tile up front
        bf16x8 kf[8], vf[8];
#pragma unroll
        for (int kk = 0; kk < 2; ++kk)
#pragma unroll
            for (int f = 0; f < 4; ++f)
                kf[kk * 4 + f] = *(const bf16x8*)&Kp[(size_t)(k0 + kk * 16 + lr) * DHEAD + f * 32 + lk * 8];
#pragma unroll
        for (int nf = 0; nf < 8; ++nf)
            vf[nf] = *(const bf16x8*)&Vt[(size_t)(nf * 16 + lr) * S_LEN + k0 + lk * 8];
        // ---- S = Q K^T (scores arrive pre-scaled; q carries 1/sqrt(Dh))
        f32x4 sc[2] = {};
#pragma unroll
        for (int kk = 0; kk < 2; ++kk)
#pragma unroll
            for (int f = 0; f < 4; ++f)
                sc[kk] = MFMA(qf[f], kf[kk * 4 + f], sc[kk]);
        // prior-iter P reads must complete before overwriting (per-wave buffer)
        asm volatile("s_waitcnt lgkmcnt(0)" ::: "memory");
        // ---- max-free softmax: p = exp(s); per-lane partial row sums
#pragma unroll
        for (int r = 0; r < 4; ++r) {
            const int qr = qbase + lk * 4 + r;
            float s0 = sc[0][r];
            float s1 = sc[1][r];
            if (k0 + lr > qr) s0 = -1e30f;
            if (k0 + 16 + lr > qr) s1 = -1e30f;
            float p0 = __expf(s0);
            float p1 = __expf(s1);
            lsum[r] += p0 + p1;
            p_lds[wave][lk * 4 + r][lr] = (__bf16)p0;
            p_lds[wave][lk * 4 + r][lr + 16] = (__bf16)p1;
        }
        asm volatile("s_waitcnt lgkmcnt(0)" ::: "memory");
        // ---- PV: attended += P(16x32) * V(32x128)
        bf16x8 pf = *(const bf16x8*)&p_lds[wave][lr][lk * 8];
#pragma unroll
        for (int nf = 0; nf < 8; ++nf)
            acc[nf] = MFMA(pf, vf[nf], acc[nf]);
    }
    // ---- one cross-lane sum at the end (16-lane groups share a row set)
#pragma unroll
    for (int r = 0; r < 4; ++r) {
        lsum[r] += __shfl_xor(lsum[r], 1);
        lsum[r] += __shfl_xor(lsum[r], 2);
        lsum[r] += __shfl_xor(lsum[r], 4);
        lsum[r] += __shfl_xor(lsum[r], 8);
    }
    // ---- normalize + store (att row-major [B*S][2048])
#pragma unroll
    for (int nf = 0; nf < 8; ++nf)
#pragma unroll
        for (int r = 0; r < 4; ++r) {
            int qr = qbase + lk * 4 + r;
            float o = acc[nf][r] / lsum[r];
            att[((size_t)(b * S_LEN) + qr) * DMODEL + h * DHEAD + nf * 16 + lr] = (__bf16)o;
        }
}

// ---------------------------------------------------------------------------
extern "C" void kernel_launch(void* const* d_in, const int* in_sizes, int n_in,
                              void* d_out, int out_size, void* d_ws, size_t ws_size,
                              hipStream_t stream) {
    const float* qkv = (const float*)d_in[0];
    const float* Wq  = (const float*)d_in[1];
    const float* Wk  = (const float*)d_in[2];
    const float* Wv  = (const float*)d_in[3];
    const float* Wo  = (const float*)d_in[4];
    const float* qg  = (const float*)d_in[5];
    const float* kg  = (const float*)d_in[6];
    float* out = (float*)d_out;

    size_t off = 0;
    char* wsb = (char*)d_ws;
    auto alloc = [&](size_t n) {
        char* p = wsb + off;
        off += (n + 255) & ~(size_t)255;
        return (void*)p;
    };
    const size_t M = (size_t)B_SZ * S_LEN;  // 4096
    float* cosT  = (float*)alloc((size_t)S_LEN * 64 * 4);
    float* sinT  = (float*)alloc((size_t)S_LEN * 64 * 4);
    float* q_tmp = (float*)alloc(M * 2048 * 4);
    float* k_tmp = (float*)alloc(M * 512 * 4);
    float* v_tmp = (float*)alloc(M * 512 * 4);
    __bf16* qb   = (__bf16*)alloc((size_t)B_SZ * NHEADS * S_LEN * DHEAD * 2);
    __bf16* kb   = (__bf16*)alloc((size_t)B_SZ * NKV * S_LEN * DHEAD * 2);
    __bf16* vt   = (__bf16*)alloc((size_t)B_SZ * NKV * DHEAD * S_LEN * 2);
    __bf16* att  = (__bf16*)alloc(M * DMODEL * 2);

    rope_tables_kernel<<<(S_LEN * 64) / 256, 256, 0, stream>>>(cosT, sinT);
    qkv_proj_kernel<<<dim3(M / 128, 24), 256, 0, stream>>>(qkv, Wq, Wk, Wv,
                                                           q_tmp, k_tmp, v_tmp);
    postproc_kernel<<<dim3(M), 256, 0, stream>>>(q_tmp, k_tmp, qg, kg, cosT, sinT, qb, kb);
    v_transpose_kernel<<<dim3(B_SZ * NKV, S_LEN / 64, DHEAD / 64), 256, 0, stream>>>(v_tmp, vt);
    flash_kernel<<<dim3(B_SZ * NHEADS, 32), 256, 0, stream>>>(qb, kb, vt, att);
    out_proj_kernel<<<dim3(M / 128, DMODEL / 128), 256, 0, stream>>>(att, Wo, out);
}

// Round 3
// 250.084 us; speedup vs baseline: 1.8726x; 1.6637x over previous
//
#include <hip/hip_runtime.h>

#define S_LEN 2048
#define B_SZ 2
#define DMODEL 2048
#define NHEADS 16
#define NKV 4
#define DHEAD 128
#define SCALE 0.08838834764831845f  // 1/sqrt(128)
#define KVB 32

typedef __bf16 bf16x8 __attribute__((ext_vector_type(8)));
typedef __bf16 bf16x4 __attribute__((ext_vector_type(4)));
typedef float f32x4 __attribute__((ext_vector_type(4)));

#define MFMA(a, b, c) __builtin_amdgcn_mfma_f32_16x16x32_bf16(a, b, c, 0, 0, 0)

__device__ __forceinline__ void gload_lds16(const __bf16* g, __bf16* l) {
    __builtin_amdgcn_global_load_lds(
        (const __attribute__((address_space(1))) unsigned int*)g,
        (__attribute__((address_space(3))) unsigned int*)l, 16, 0, 0);
}

// ---------------------------------------------------------------------------
// RoPE tables: cos/sin [S][64]
// ---------------------------------------------------------------------------
__global__ void rope_tables_kernel(float* __restrict__ cosT, float* __restrict__ sinT) {
    int i = blockIdx.x * 256 + threadIdx.x;       // S*64 entries
    int s = i >> 6, d = i & 63;
    float freq = powf(10000.0f, -(2.0f * (float)d) / 128.0f);
    float ang = (float)s * freq;
    cosT[i] = cosf(ang);
    sinT[i] = sinf(ang);
}

// ---------------------------------------------------------------------------
// GEMM: C[m][n] = sum_k A[m][k] * W[n][k]   (W is [N][K] row-major = B^T)
// 128x128 tile, BK=32, 256 threads = 4 waves (2x2 of 64x64), 16x16x32 bf16 MFMA
// ---------------------------------------------------------------------------
template <bool ABF16>
__device__ __forceinline__ void gemm_bt_body(const void* __restrict__ Av,
                                             const float* __restrict__ W,
                                             float* __restrict__ C, int ldc,
                                             int bm, int bn, int K) {
    __shared__ alignas(16) __bf16 As[128][32];
    __shared__ alignas(16) __bf16 Bs[128][32];
    const int tid = threadIdx.x;
    const int lane = tid & 63;
    const int wave = tid >> 6;
    const int lr = lane & 15;        // row-in-16 for A/B frags, col for C
    const int lk = lane >> 4;        // k-chunk id 0..3, row-group for C
    const int wm = (wave >> 1) * 64;
    const int wn = (wave & 1) * 64;

    f32x4 acc[4][4] = {};

    for (int k0 = 0; k0 < K; k0 += 32) {
        __syncthreads();  // prior-iter LDS reads done before overwrite
        if constexpr (ABF16) {
            const __bf16* A = (const __bf16*)Av;
#pragma unroll
            for (int i = 0; i < 2; ++i) {
                int idx = tid + i * 256;          // 512 chunks of 8 bf16
                int row = idx >> 2, c8 = idx & 3;
                *(bf16x8*)&As[row][c8 * 8] =
                    *(const bf16x8*)&A[(size_t)(bm + row) * K + k0 + c8 * 8];
            }
        } else {
            const float* A = (const float*)Av;
#pragma unroll
            for (int i = 0; i < 4; ++i) {
                int idx = tid + i * 256;          // 1024 chunks of 4 floats
                int row = idx >> 3, c4 = idx & 7;
                float4 v = *(const float4*)&A[(size_t)(bm + row) * K + k0 + c4 * 4];
                bf16x4 bv = {(__bf16)v.x, (__bf16)v.y, (__bf16)v.z, (__bf16)v.w};
                *(bf16x4*)&As[row][c4 * 4] = bv;
            }
        }
#pragma unroll
        for (int i = 0; i < 4; ++i) {
            int idx = tid + i * 256;
            int row = idx >> 3, c4 = idx & 7;
            float4 v = *(const float4*)&W[(size_t)(bn + row) * K + k0 + c4 * 4];
            bf16x4 bv = {(__bf16)v.x, (__bf16)v.y, (__bf16)v.z, (__bf16)v.w};
            *(bf16x4*)&Bs[row][c4 * 4] = bv;
        }
        __syncthreads();

        bf16x8 af[4], bfr[4];
#pragma unroll
        for (int i = 0; i < 4; ++i) {
            af[i]  = *(const bf16x8*)&As[wm + i * 16 + lr][lk * 8];
            bfr[i] = *(const bf16x8*)&Bs[wn + i * 16 + lr][lk * 8];
        }
#pragma unroll
        for (int mi = 0; mi < 4; ++mi)
#pragma unroll
            for (int ni = 0; ni < 4; ++ni)
                acc[mi][ni] = MFMA(af[mi], bfr[ni], acc[mi][ni]);
    }

#pragma unroll
    for (int mi = 0; mi < 4; ++mi)
#pragma unroll
        for (int ni = 0; ni < 4; ++ni)
#pragma unroll
            for (int r = 0; r < 4; ++r) {
                int row = bm + wm + mi * 16 + lk * 4 + r;
                int col = bn + wn + ni * 16 + lr;
                C[(size_t)row * ldc + col] = acc[mi][ni][r];
            }
}

// grid (M/128, 24): ny 0..15 -> Q, 16..19 -> K, 20..23 -> V
__global__ __launch_bounds__(256) void qkv_proj_kernel(
    const float* __restrict__ qkv, const float* __restrict__ Wq,
    const float* __restrict__ Wk, const float* __restrict__ Wv,
    float* __restrict__ q_tmp, float* __restrict__ k_tmp, float* __restrict__ v_tmp) {
    int bm = blockIdx.x * 128;
    int ny = blockIdx.y;
    const float* W;
    float* C;
    int ldc, bn;
    if (ny < 16)      { W = Wq; C = q_tmp; ldc = 2048; bn = ny * 128; }
    else if (ny < 20) { W = Wk; C = k_tmp; ldc = 512;  bn = (ny - 16) * 128; }
    else              { W = Wv; C = v_tmp; ldc = 512;  bn = (ny - 20) * 128; }
    gemm_bt_body<false>(qkv, W, C, ldc, bm, bn, 2048);
}

__global__ __launch_bounds__(256) void out_proj_kernel(
    const __bf16* __restrict__ att, const float* __restrict__ Wo,
    float* __restrict__ out) {
    gemm_bt_body<true>(att, Wo, out, 2048, blockIdx.x * 128, blockIdx.y * 128, 2048);
}

// ---------------------------------------------------------------------------
// RMSNorm + RoPE + bf16 + transpose for Q,K.  grid (B*S), 256 threads.
// qb: [B,H,S,Dh] (pre-scaled by 1/sqrt(Dh))  kb: [B,KV,S,Dh]
// ---------------------------------------------------------------------------
__global__ __launch_bounds__(256) void postproc_kernel(
    const float* __restrict__ q_tmp, const float* __restrict__ k_tmp,
    const float* __restrict__ qg, const float* __restrict__ kg,
    const float* __restrict__ cosT, const float* __restrict__ sinT,
    __bf16* __restrict__ qb, __bf16* __restrict__ kb) {
    int bs = blockIdx.x;
    int b = bs >> 11, s = bs & 2047;
    int wave = threadIdx.x >> 6, lane = threadIdx.x & 63;
    float c  = cosT[s * 64 + lane];
    float sn = sinT[s * 64 + lane];
    float g1q = qg[lane], g2q = qg[lane + 64];
    float g1k = kg[lane], g2k = kg[lane + 64];

    for (int h = wave; h < NHEADS; h += 4) {
        const float* row = q_tmp + (size_t)bs * 2048 + h * 128;
        float x1 = row[lane], x2 = row[lane + 64];
        float ss = x1 * x1 + x2 * x2;
#pragma unroll
        for (int m = 1; m < 64; m <<= 1) ss += __shfl_xor(ss, m);
        float rs = rsqrtf(ss * (1.0f / 128.0f) + 1e-6f);
        float n1 = x1 * rs * g1q, n2 = x2 * rs * g2q;
        // fold the attention score scale into q
        float y1 = (n1 * c - n2 * sn) * SCALE;
        float y2 = (n2 * c + n1 * sn) * SCALE;
        __bf16* orow = qb + (((size_t)(b * NHEADS + h)) * S_LEN + s) * DHEAD;
        orow[lane] = (__bf16)y1;
        orow[lane + 64] = (__bf16)y2;
    }
    int h = wave;
    if (h < NKV) {
        const float* row = k_tmp + (size_t)bs * 512 + h * 128;
        float x1 = row[lane], x2 = row[lane + 64];
        float ss = x1 * x1 + x2 * x2;
#pragma unroll
        for (int m = 1; m < 64; m <<= 1) ss += __shfl_xor(ss, m);
        float rs = rsqrtf(ss * (1.0f / 128.0f) + 1e-6f);
        float n1 = x1 * rs * g1k, n2 = x2 * rs * g2k;
        float y1 = n1 * c - n2 * sn;
        float y2 = n2 * c + n1 * sn;
        __bf16* orow = kb + (((size_t)(b * NKV + h)) * S_LEN + s) * DHEAD;
        orow[lane] = (__bf16)y1;
        orow[lane + 64] = (__bf16)y2;
    }
}

// ---------------------------------------------------------------------------
// V transpose: v_tmp fp32 [B*S][512] -> vt bf16 [B,KV,Dh,S]
// ---------------------------------------------------------------------------
__global__ __launch_bounds__(256) void v_transpose_kernel(
    const float* __restrict__ v_tmp, __bf16* __restrict__ vt) {
    int bkv = blockIdx.x;
    int b = bkv >> 2, kvh = bkv & 3;
    int s0 = blockIdx.y * 64, d0 = blockIdx.z * 64;
    __shared__ float tile[64][65];
#pragma unroll
    for (int i = 0; i < 16; ++i) {
        int idx = threadIdx.x + i * 256;
        int r = idx >> 6, cc = idx & 63;
        tile[r][cc] = v_tmp[((size_t)(b * S_LEN) + s0 + r) * 512 + kvh * 128 + d0 + cc];
    }
    __syncthreads();
#pragma unroll
    for (int i = 0; i < 16; ++i) {
        int idx = threadIdx.x + i * 256;
        int r = idx >> 6, cc = idx & 63;   // r = d-local, cc = s-local
        vt[((size_t)bkv * DHEAD + d0 + r) * S_LEN + s0 + cc] = (__bf16)tile[cc][r];
    }
}

// ---------------------------------------------------------------------------
// Causal flash attention with block-shared double-buffered K/V LDS staging.
// grid (B*H, 16), 256 threads = 4 waves.
// Block j handles 64-row strips j and 31-j; wave w owns 16-row frags of each.
// K_lds rows (256B) swizzled byte^=(row&7)<<4; V_lds rows (64B) byte^=(row&3)<<4.
// Staged via global_load_lds: linear LDS dest + inverse-swizzled global source.
// qb [B,H,S,Dh] (q pre-scaled), kb [B,KV,S,Dh], vt [B,KV,Dh,S] -> att [B,S,H*Dh]
// ---------------------------------------------------------------------------
__global__ __launch_bounds__(256, 2) void flash_kernel(
    const __bf16* __restrict__ qb, const __bf16* __restrict__ kb,
    const __bf16* __restrict__ vt, __bf16* __restrict__ att) {
    __shared__ alignas(16) __bf16 K_lds[2][32 * 128];   // 8KB each
    __shared__ alignas(16) __bf16 V_lds[2][128 * 32];   // 8KB each
    __shared__ alignas(16) __bf16 p_lds[4][16][40];

    const int bh = blockIdx.x;
    const int b = bh >> 4, h = bh & 15, kv = h >> 2;
    const int j = blockIdx.y;  // 0..15
    const int lane = threadIdx.x & 63, wave = threadIdx.x >> 6;
    const int lr = lane & 15, lk = lane >> 4;

    const int qloB = j * 64 + wave * 16;
    const int qhiB = (31 - j) * 64 + wave * 16;
    const int ntL  = ((qloB + 15) >> 5) + 1;   // per-wave low-frag tiles
    const int ntHw = ((qhiB + 15) >> 5) + 1;   // per-wave high-frag tiles
    const int ntH  = 64 - 2 * j;               // block-uniform staged tiles

    const __bf16* Qp = qb + ((size_t)(b * NHEADS + h)) * S_LEN * DHEAD;
    const __bf16* Kp = kb + ((size_t)(b * NKV + kv)) * S_LEN * DHEAD;
    const __bf16* Vt = vt + ((size_t)(b * NKV + kv)) * DHEAD * S_LEN;

    bf16x8 qlo[4], qhi[4];
#pragma unroll
    for (int f = 0; f < 4; ++f) {
        qlo[f] = *(const bf16x8*)&Qp[(size_t)(qloB + lr) * DHEAD + f * 32 + lk * 8];
        qhi[f] = *(const bf16x8*)&Qp[(size_t)(qhiB + lr) * DHEAD + f * 32 + lk * 8];
    }

    // staging lane constants (inverse-swizzled global source)
    const int c0 = 2 * wave;
    const int l4 = lane >> 4, l15 = lane & 15;
    const int l2 = lane >> 2, l3 = lane & 3;
    const int vcol = ((l3 ^ (l2 & 3)) << 3);

    auto stage = [&](int bufi, int t) {
        const int k0s = t * KVB;
#pragma unroll
        for (int i = 0; i < 2; ++i) {
            const int c = c0 + i;
            const int rK = c * 4 + l4;
            const int kcol = ((l15 ^ (rK & 7)) << 3);
            gload_lds16(Kp + (size_t)(k0s + rK) * DHEAD + kcol, &K_lds[bufi][c * 512]);
            const int rV = c * 16 + l2;
            gload_lds16(Vt + (size_t)rV * S_LEN + k0s + vcol, &V_lds[bufi][c * 512]);
        }
    };

    f32x4 accL[8] = {}, accH[8] = {};
    float lsumL[4] = {0.f, 0.f, 0.f, 0.f}, lsumH[4] = {0.f, 0.f, 0.f, 0.f};
    const int swzK = (lr & 7) << 4;
    const int swzV = (lr & 3) << 4;

    auto frag_step = [&](const bf16x8 (&qf)[4], int qbase, f32x4 (&acc)[8],
                         float (&lsum)[4], const bf16x8 (&kf)[8],
                         const bf16x8 (&vf)[8], int k0) {
        f32x4 sc[2] = {};
#pragma unroll
        for (int kk = 0; kk < 2; ++kk)
#pragma unroll
            for (int f = 0; f < 4; ++f)
                sc[kk] = MFMA(qf[f], kf[kk * 4 + f], sc[kk]);
        // prior p_lds reads (this wave) must complete before overwrite
        asm volatile("s_waitcnt lgkmcnt(0)" ::: "memory");
#pragma unroll
        for (int r = 0; r < 4; ++r) {
            const int qr = qbase + lk * 4 + r;
            float s0 = sc[0][r], s1 = sc[1][r];
            if (k0 + lr > qr) s0 = -1e30f;
            if (k0 + 16 + lr > qr) s1 = -1e30f;
            float p0 = __expf(s0), p1 = __expf(s1);
            lsum[r] += p0 + p1;
            p_lds[wave][lk * 4 + r][lr] = (__bf16)p0;
            p_lds[wave][lk * 4 + r][lr + 16] = (__bf16)p1;
        }
        asm volatile("s_waitcnt lgkmcnt(0)" ::: "memory");
        bf16x8 pf = *(const bf16x8*)&p_lds[wave][lr][lk * 8];
#pragma unroll
        for (int nf = 0; nf < 8; ++nf)
            acc[nf] = MFMA(pf, vf[nf], acc[nf]);
    };

    int cur = 0;
    stage(0, 0);
    __syncthreads();   // drains stage vmcnt before first use
    for (int t = 0; t < ntH; ++t) {
        if (t + 1 < ntH) stage(cur ^ 1, t + 1);
        const int k0 = t * KVB;
        bf16x8 kf[8], vf[8];
#pragma unroll
        for (int kk = 0; kk < 2; ++kk)
#pragma unroll
            for (int f = 0; f < 4; ++f) {
                const int cb = (f * 64 + lk * 16) ^ swzK;
                kf[kk * 4 + f] =
                    *(const bf16x8*)((const char*)&K_lds[cur][(kk * 16 + lr) * 128] + cb);
            }
#pragma unroll
        for (int nf = 0; nf < 8; ++nf) {
            const int cb = (lk * 16) ^ swzV;
            vf[nf] = *(const bf16x8*)((const char*)&V_lds[cur][(nf * 16 + lr) * 32] + cb);
        }
        if (t < ntHw) frag_step(qhi, qhiB, accH, lsumH, kf, vf, k0);
        if (t < ntL)  frag_step(qlo, qloB, accL, lsumL, kf, vf, k0);
        __syncthreads();   // all waves done with buf[cur]; next stage reuses it
        cur ^= 1;
    }

    // ---- cross-lane row sums
#pragma unroll
    for (int r = 0; r < 4; ++r) {
#pragma unroll
        for (int m = 1; m < 16; m <<= 1) {
            lsumL[r] += __shfl_xor(lsumL[r], m);
            lsumH[r] += __shfl_xor(lsumH[r], m);
        }
    }
    // ---- normalize + store (att row-major [B*S][2048])
#pragma unroll
    for (int nf = 0; nf < 8; ++nf)
#pragma unroll
        for (int r = 0; r < 4; ++r) {
            int qrL = qloB + lk * 4 + r;
            int qrH = qhiB + lk * 4 + r;
            att[((size_t)(b * S_LEN) + qrL) * DMODEL + h * DHEAD + nf * 16 + lr] =
                (__bf16)(accL[nf][r] / lsumL[r]);
            att[((size_t)(b * S_LEN) + qrH) * DMODEL + h * DHEAD + nf * 16 + lr] =
                (__bf16)(accH[nf][r] / lsumH[r]);
        }
}

// ---------------------------------------------------------------------------
extern "C" void kernel_launch(void* const* d_in, const int* in_sizes, int n_in,
                              void* d_out, int out_size, void* d_ws, size_t ws_size,
                              hipStream_t stream) {
    const float* qkv = (const float*)d_in[0];
    const float* Wq  = (const float*)d_in[1];
    const float* Wk  = (const float*)d_in[2];
    const float* Wv  = (const float*)d_in[3];
    const float* Wo  = (const float*)d_in[4];
    const float* qg  = (const float*)d_in[5];
    const float* kg  = (const float*)d_in[6];
    float* out = (float*)d_out;

    size_t off = 0;
    char* wsb = (char*)d_ws;
    auto alloc = [&](size_t n) {
        char* p = wsb + off;
        off += (n + 255) & ~(size_t)255;
        return (void*)p;
    };
    const size_t M = (size_t)B_SZ * S_LEN;  // 4096
    float* cosT  = (float*)alloc((size_t)S_LEN * 64 * 4);
    float* sinT  = (float*)alloc((size_t)S_LEN * 64 * 4);
    float* q_tmp = (float*)alloc(M * 2048 * 4);
    float* k_tmp = (float*)alloc(M * 512 * 4);
    float* v_tmp = (float*)alloc(M * 512 * 4);
    __bf16* qb   = (__bf16*)alloc((size_t)B_SZ * NHEADS * S_LEN * DHEAD * 2);
    __bf16* kb   = (__bf16*)alloc((size_t)B_SZ * NKV * S_LEN * DHEAD * 2);
    __bf16* vt   = (__bf16*)alloc((size_t)B_SZ * NKV * DHEAD * S_LEN * 2);
    __bf16* att  = (__bf16*)alloc(M * DMODEL * 2);

    rope_tables_kernel<<<(S_LEN * 64) / 256, 256, 0, stream>>>(cosT, sinT);
    qkv_proj_kernel<<<dim3(M / 128, 24), 256, 0, stream>>>(qkv, Wq, Wk, Wv,
                                                           q_tmp, k_tmp, v_tmp);
    postproc_kernel<<<dim3(M), 256, 0, stream>>>(q_tmp, k_tmp, qg, kg, cosT, sinT, qb, kb);
    v_transpose_kernel<<<dim3(B_SZ * NKV, S_LEN / 64, DHEAD / 64), 256, 0, stream>>>(v_tmp, vt);
    flash_kernel<<<dim3(B_SZ * NHEADS, 16), 256, 0, stream>>>(qb, kb, vt, att);
    out_proj_kernel<<<dim3(M / 128, DMODEL / 128), 256, 0, stream>>>(att, Wo, out);
}

// Round 5
// 247.082 us; speedup vs baseline: 1.8954x; 1.0121x over previous
//
#include <hip/hip_runtime.h>

#define S_LEN 2048
#define B_SZ 2
#define DMODEL 2048
#define NHEADS 16
#define NKV 4
#define DHEAD 128
#define SCALE 0.08838834764831845f  // 1/sqrt(128)
#define KVB 32

typedef __bf16 bf16x8 __attribute__((ext_vector_type(8)));
typedef __bf16 bf16x4 __attribute__((ext_vector_type(4)));
typedef float f32x4 __attribute__((ext_vector_type(4)));

#define MFMA(a, b, c) __builtin_amdgcn_mfma_f32_16x16x32_bf16(a, b, c, 0, 0, 0)

__device__ __forceinline__ void gload_lds16(const __bf16* g, __bf16* l) {
    __builtin_amdgcn_global_load_lds(
        (const __attribute__((address_space(1))) unsigned int*)g,
        (__attribute__((address_space(3))) unsigned int*)l, 16, 0, 0);
}

// ---------------------------------------------------------------------------
// RoPE tables: cos/sin [S][64]
// ---------------------------------------------------------------------------
__global__ void rope_tables_kernel(float* __restrict__ cosT, float* __restrict__ sinT) {
    int i = blockIdx.x * 256 + threadIdx.x;       // S*64 entries
    int s = i >> 6, d = i & 63;
    float freq = powf(10000.0f, -(2.0f * (float)d) / 128.0f);
    float ang = (float)s * freq;
    cosT[i] = cosf(ang);
    sinT[i] = sinf(ang);
}

// ---------------------------------------------------------------------------
// fp32 -> bf16 convert, 5 regions (qkv, Wq, Wk, Wv, Wo), 16B stores.
// grid (512, 5) x 256 threads, grid-stride per region in units of 8 floats.
// ---------------------------------------------------------------------------
__global__ __launch_bounds__(256) void convert_kernel(
    const float* __restrict__ s0, const float* __restrict__ s1,
    const float* __restrict__ s2, const float* __restrict__ s3,
    const float* __restrict__ s4,
    __bf16* __restrict__ d0, __bf16* __restrict__ d1, __bf16* __restrict__ d2,
    __bf16* __restrict__ d3, __bf16* __restrict__ d4) {
    const float* s;
    __bf16* d;
    int n8;
    switch (blockIdx.y) {
        case 0: s = s0; d = d0; n8 = (B_SZ * S_LEN * DMODEL) / 8; break;      // qkv
        case 1: s = s1; d = d1; n8 = (DMODEL * DMODEL) / 8; break;            // Wq
        case 2: s = s2; d = d2; n8 = (NKV * DHEAD * DMODEL) / 8; break;       // Wk
        case 3: s = s3; d = d3; n8 = (NKV * DHEAD * DMODEL) / 8; break;       // Wv
        default: s = s4; d = d4; n8 = (DMODEL * DMODEL) / 8; break;           // Wo
    }
    for (int i = blockIdx.x * 256 + threadIdx.x; i < n8; i += 512 * 256) {
        float4 a = ((const float4*)s)[2 * i];
        float4 b = ((const float4*)s)[2 * i + 1];
        bf16x8 o = {(__bf16)a.x, (__bf16)a.y, (__bf16)a.z, (__bf16)a.w,
                    (__bf16)b.x, (__bf16)b.y, (__bf16)b.z, (__bf16)b.w};
        *(bf16x8*)&d[i * 8] = o;
    }
}

// ---------------------------------------------------------------------------
// GEMM (m97 structure): C[m][n] = sum_k A[m][k] * W[n][k], all-bf16 operands.
// 128x128 tile, BK=32, 256 threads = 4 waves (2x2 of 64x64), 16x16x32 MFMA.
// Staging via global_load_lds width=16 (linear LDS, 4 issues/thread/K-step).
// ---------------------------------------------------------------------------
__device__ __forceinline__ void gemm_bt_bf16(const __bf16* __restrict__ A,
                                             const __bf16* __restrict__ W,
                                             float* __restrict__ C, int ldc,
                                             int bm, int bn, int K) {
    __shared__ alignas(16) __bf16 As[128][32];
    __shared__ alignas(16) __bf16 Bs[128][32];
    const int tid = threadIdx.x;
    const int lane = tid & 63;
    const int wave = tid >> 6;
    const int lr = lane & 15;        // row-in-16 for A/B frags, col for C
    const int lk = lane >> 4;        // k-chunk id 0..3, row-group for C
    const int wm = (wave >> 1) * 64;
    const int wn = (wave & 1) * 64;
    const int srow = lane >> 2;      // staging: row-in-16 (4 chunks per 64B row)
    const int sc8 = (lane & 3) * 8;  // staging: element offset within row

    f32x4 acc[4][4] = {};

    for (int k0 = 0; k0 < K; k0 += 32) {
        // stage next tile: 8KB A + 8KB B, 16B per lane per issue
#pragma unroll
        for (int i = 0; i < 2; ++i) {
            const int row = i * 64 + wave * 16 + srow;
            gload_lds16(A + (size_t)(bm + row) * K + k0 + sc8,
                        (__bf16*)As + i * 2048 + wave * 512);
            gload_lds16(W + (size_t)(bn + row) * K + k0 + sc8,
                        (__bf16*)Bs + i * 2048 + wave * 512);
        }
        __syncthreads();   // drains vmcnt -> staged tile visible to all waves

        bf16x8 af[4], bfr[4];
#pragma unroll
        for (int i = 0; i < 4; ++i) {
            af[i]  = *(const bf16x8*)&As[wm + i * 16 + lr][lk * 8];
            bfr[i] = *(const bf16x8*)&Bs[wn + i * 16 + lr][lk * 8];
        }
#pragma unroll
        for (int mi = 0; mi < 4; ++mi)
#pragma unroll
            for (int ni = 0; ni < 4; ++ni)
                acc[mi][ni] = MFMA(af[mi], bfr[ni], acc[mi][ni]);
        __syncthreads();   // all waves done reading before next stage overwrites
    }

#pragma unroll
    for (int mi = 0; mi < 4; ++mi)
#pragma unroll
        for (int ni = 0; ni < 4; ++ni)
#pragma unroll
            for (int r = 0; r < 4; ++r) {
                int row = bm + wm + mi * 16 + lk * 4 + r;
                int col = bn + wn + ni * 16 + lr;
                C[(size_t)row * ldc + col] = acc[mi][ni][r];
            }
}

// grid (M/128, 24): ny 0..15 -> Q, 16..19 -> K, 20..23 -> V
__global__ __launch_bounds__(256) void qkv_proj_kernel(
    const __bf16* __restrict__ qkvb, const __bf16* __restrict__ Wq,
    const __bf16* __restrict__ Wk, const __bf16* __restrict__ Wv,
    float* __restrict__ q_tmp, float* __restrict__ k_tmp, float* __restrict__ v_tmp) {
    int bm = blockIdx.x * 128;
    int ny = blockIdx.y;
    const __bf16* W;
    float* C;
    int ldc, bn;
    if (ny < 16)      { W = Wq; C = q_tmp; ldc = 2048; bn = ny * 128; }
    else if (ny < 20) { W = Wk; C = k_tmp; ldc = 512;  bn = (ny - 16) * 128; }
    else              { W = Wv; C = v_tmp; ldc = 512;  bn = (ny - 20) * 128; }
    gemm_bt_bf16(qkvb, W, C, ldc, bm, bn, 2048);
}

__global__ __launch_bounds__(256) void out_proj_kernel(
    const __bf16* __restrict__ att, const __bf16* __restrict__ Wo,
    float* __restrict__ out) {
    gemm_bt_bf16(att, Wo, out, 2048, blockIdx.x * 128, blockIdx.y * 128, 2048);
}

// ---------------------------------------------------------------------------
// RMSNorm + RoPE + bf16 + transpose for Q,K.  grid (B*S), 256 threads.
// qb: [B,H,S,Dh] (pre-scaled by 1/sqrt(Dh))  kb: [B,KV,S,Dh]
// ---------------------------------------------------------------------------
__global__ __launch_bounds__(256) void postproc_kernel(
    const float* __restrict__ q_tmp, const float* __restrict__ k_tmp,
    const float* __restrict__ qg, const float* __restrict__ kg,
    const float* __restrict__ cosT, const float* __restrict__ sinT,
    __bf16* __restrict__ qb, __bf16* __restrict__ kb) {
    int bs = blockIdx.x;
    int b = bs >> 11, s = bs & 2047;
    int wave = threadIdx.x >> 6, lane = threadIdx.x & 63;
    float c  = cosT[s * 64 + lane];
    float sn = sinT[s * 64 + lane];
    float g1q = qg[lane], g2q = qg[lane + 64];
    float g1k = kg[lane], g2k = kg[lane + 64];

    for (int h = wave; h < NHEADS; h += 4) {
        const float* row = q_tmp + (size_t)bs * 2048 + h * 128;
        float x1 = row[lane], x2 = row[lane + 64];
        float ss = x1 * x1 + x2 * x2;
#pragma unroll
        for (int m = 1; m < 64; m <<= 1) ss += __shfl_xor(ss, m);
        float rs = rsqrtf(ss * (1.0f / 128.0f) + 1e-6f);
        float n1 = x1 * rs * g1q, n2 = x2 * rs * g2q;
        // fold the attention score scale into q
        float y1 = (n1 * c - n2 * sn) * SCALE;
        float y2 = (n2 * c + n1 * sn) * SCALE;
        __bf16* orow = qb + (((size_t)(b * NHEADS + h)) * S_LEN + s) * DHEAD;
        orow[lane] = (__bf16)y1;
        orow[lane + 64] = (__bf16)y2;
    }
    int h = wave;
    if (h < NKV) {
        const float* row = k_tmp + (size_t)bs * 512 + h * 128;
        float x1 = row[lane], x2 = row[lane + 64];
        float ss = x1 * x1 + x2 * x2;
#pragma unroll
        for (int m = 1; m < 64; m <<= 1) ss += __shfl_xor(ss, m);
        float rs = rsqrtf(ss * (1.0f / 128.0f) + 1e-6f);
        float n1 = x1 * rs * g1k, n2 = x2 * rs * g2k;
        float y1 = n1 * c - n2 * sn;
        float y2 = n2 * c + n1 * sn;
        __bf16* orow = kb + (((size_t)(b * NKV + h)) * S_LEN + s) * DHEAD;
        orow[lane] = (__bf16)y1;
        orow[lane + 64] = (__bf16)y2;
    }
}

// ---------------------------------------------------------------------------
// V transpose: v_tmp fp32 [B*S][512] -> vt bf16 [B,KV,Dh,S]
// ---------------------------------------------------------------------------
__global__ __launch_bounds__(256) void v_transpose_kernel(
    const float* __restrict__ v_tmp, __bf16* __restrict__ vt) {
    int bkv = blockIdx.x;
    int b = bkv >> 2, kvh = bkv & 3;
    int s0 = blockIdx.y * 64, d0 = blockIdx.z * 64;
    __shared__ float tile[64][65];
#pragma unroll
    for (int i = 0; i < 16; ++i) {
        int idx = threadIdx.x + i * 256;
        int r = idx >> 6, cc = idx & 63;
        tile[r][cc] = v_tmp[((size_t)(b * S_LEN) + s0 + r) * 512 + kvh * 128 + d0 + cc];
    }
    __syncthreads();
#pragma unroll
    for (int i = 0; i < 16; ++i) {
        int idx = threadIdx.x + i * 256;
        int r = idx >> 6, cc = idx & 63;   // r = d-local, cc = s-local
        vt[((size_t)bkv * DHEAD + d0 + r) * S_LEN + s0 + cc] = (__bf16)tile[cc][r];
    }
}

// ---------------------------------------------------------------------------
// Causal flash attention with block-shared double-buffered K/V LDS staging.
// grid (B*H, 16), 256 threads = 4 waves.
// ---------------------------------------------------------------------------
__global__ __launch_bounds__(256, 2) void flash_kernel(
    const __bf16* __restrict__ qb, const __bf16* __restrict__ kb,
    const __bf16* __restrict__ vt, __bf16* __restrict__ att) {
    __shared__ alignas(16) __bf16 K_lds[2][32 * 128];   // 8KB each
    __shared__ alignas(16) __bf16 V_lds[2][128 * 32];   // 8KB each
    __shared__ alignas(16) __bf16 p_lds[4][16][40];

    const int bh = blockIdx.x;
    const int b = bh >> 4, h = bh & 15, kv = h >> 2;
    const int j = blockIdx.y;  // 0..15
    const int lane = threadIdx.x & 63, wave = threadIdx.x >> 6;
    const int lr = lane & 15, lk = lane >> 4;

    const int qloB = j * 64 + wave * 16;
    const int qhiB = (31 - j) * 64 + wave * 16;
    const int ntL  = ((qloB + 15) >> 5) + 1;   // per-wave low-frag tiles
    const int ntHw = ((qhiB + 15) >> 5) + 1;   // per-wave high-frag tiles
    const int ntH  = 64 - 2 * j;               // block-uniform staged tiles

    const __bf16* Qp = qb + ((size_t)(b * NHEADS + h)) * S_LEN * DHEAD;
    const __bf16* Kp = kb + ((size_t)(b * NKV + kv)) * S_LEN * DHEAD;
    const __bf16* Vt = vt + ((size_t)(b * NKV + kv)) * DHEAD * S_LEN;

    bf16x8 qlo[4], qhi[4];
#pragma unroll
    for (int f = 0; f < 4; ++f) {
        qlo[f] = *(const bf16x8*)&Qp[(size_t)(qloB + lr) * DHEAD + f * 32 + lk * 8];
        qhi[f] = *(const bf16x8*)&Qp[(size_t)(qhiB + lr) * DHEAD + f * 32 + lk * 8];
    }

    // staging lane constants (inverse-swizzled global source)
    const int c0 = 2 * wave;
    const int l4 = lane >> 4, l15 = lane & 15;
    const int l2 = lane >> 2, l3 = lane & 3;
    const int vcol = ((l3 ^ (l2 & 3)) << 3);

    auto stage = [&](int bufi, int t) {
        const int k0s = t * KVB;
#pragma unroll
        for (int i = 0; i < 2; ++i) {
            const int c = c0 + i;
            const int rK = c * 4 + l4;
            const int kcol = ((l15 ^ (rK & 7)) << 3);
            gload_lds16(Kp + (size_t)(k0s + rK) * DHEAD + kcol, &K_lds[bufi][c * 512]);
            const int rV = c * 16 + l2;
            gload_lds16(Vt + (size_t)rV * S_LEN + k0s + vcol, &V_lds[bufi][c * 512]);
        }
    };

    f32x4 accL[8] = {}, accH[8] = {};
    float lsumL[4] = {0.f, 0.f, 0.f, 0.f}, lsumH[4] = {0.f, 0.f, 0.f, 0.f};
    const int swzK = (lr & 7) << 4;
    const int swzV = (lr & 3) << 4;

    auto frag_step = [&](const bf16x8 (&qf)[4], int qbase, f32x4 (&acc)[8],
                         float (&lsum)[4], const bf16x8 (&kf)[8],
                         const bf16x8 (&vf)[8], int k0) {
        f32x4 sc[2] = {};
#pragma unroll
        for (int kk = 0; kk < 2; ++kk)
#pragma unroll
            for (int f = 0; f < 4; ++f)
                sc[kk] = MFMA(qf[f], kf[kk * 4 + f], sc[kk]);
        // prior p_lds reads (this wave) must complete before overwrite
        asm volatile("s_waitcnt lgkmcnt(0)" ::: "memory");
#pragma unroll
        for (int r = 0; r < 4; ++r) {
            const int qr = qbase + lk * 4 + r;
            float s0 = sc[0][r], s1 = sc[1][r];
            if (k0 + lr > qr) s0 = -1e30f;
            if (k0 + 16 + lr > qr) s1 = -1e30f;
            float p0 = __expf(s0), p1 = __expf(s1);
            lsum[r] += p0 + p1;
            p_lds[wave][lk * 4 + r][lr] = (__bf16)p0;
            p_lds[wave][lk * 4 + r][lr + 16] = (__bf16)p1;
        }
        asm volatile("s_waitcnt lgkmcnt(0)" ::: "memory");
        bf16x8 pf = *(const bf16x8*)&p_lds[wave][lr][lk * 8];
#pragma unroll
        for (int nf = 0; nf < 8; ++nf)
            acc[nf] = MFMA(pf, vf[nf], acc[nf]);
    };

    int cur = 0;
    stage(0, 0);
    __syncthreads();   // drains stage vmcnt before first use
    for (int t = 0; t < ntH; ++t) {
        if (t + 1 < ntH) stage(cur ^ 1, t + 1);
        const int k0 = t * KVB;
        bf16x8 kf[8], vf[8];
#pragma unroll
        for (int kk = 0; kk < 2; ++kk)
#pragma unroll
            for (int f = 0; f < 4; ++f) {
                const int cb = (f * 64 + lk * 16) ^ swzK;
                kf[kk * 4 + f] =
                    *(const bf16x8*)((const char*)&K_lds[cur][(kk * 16 + lr) * 128] + cb);
            }
#pragma unroll
        for (int nf = 0; nf < 8; ++nf) {
            const int cb = (lk * 16) ^ swzV;
            vf[nf] = *(const bf16x8*)((const char*)&V_lds[cur][(nf * 16 + lr) * 32] + cb);
        }
        if (t < ntHw) frag_step(qhi, qhiB, accH, lsumH, kf, vf, k0);
        if (t < ntL)  frag_step(qlo, qloB, accL, lsumL, kf, vf, k0);
        __syncthreads();   // all waves done with buf[cur]; next stage reuses it
        cur ^= 1;
    }

    // ---- cross-lane row sums
#pragma unroll
    for (int r = 0; r < 4; ++r) {
#pragma unroll
        for (int m = 1; m < 16; m <<= 1) {
            lsumL[r] += __shfl_xor(lsumL[r], m);
            lsumH[r] += __shfl_xor(lsumH[r], m);
        }
    }
    // ---- normalize + store (att row-major [B*S][2048])
#pragma unroll
    for (int nf = 0; nf < 8; ++nf)
#pragma unroll
        for (int r = 0; r < 4; ++r) {
            int qrL = qloB + lk * 4 + r;
            int qrH = qhiB + lk * 4 + r;
            att[((size_t)(b * S_LEN) + qrL) * DMODEL + h * DHEAD + nf * 16 + lr] =
                (__bf16)(accL[nf][r] / lsumL[r]);
            att[((size_t)(b * S_LEN) + qrH) * DMODEL + h * DHEAD + nf * 16 + lr] =
                (__bf16)(accH[nf][r] / lsumH[r]);
        }
}

// ---------------------------------------------------------------------------
extern "C" void kernel_launch(void* const* d_in, const int* in_sizes, int n_in,
                              void* d_out, int out_size, void* d_ws, size_t ws_size,
                              hipStream_t stream) {
    const float* qkv = (const float*)d_in[0];
    const float* Wq  = (const float*)d_in[1];
    const float* Wk  = (const float*)d_in[2];
    const float* Wv  = (const float*)d_in[3];
    const float* Wo  = (const float*)d_in[4];
    const float* qg  = (const float*)d_in[5];
    const float* kg  = (const float*)d_in[6];
    float* out = (float*)d_out;

    size_t off = 0;
    char* wsb = (char*)d_ws;
    auto alloc = [&](size_t n) {
        char* p = wsb + off;
        off += (n + 255) & ~(size_t)255;
        return (void*)p;
    };
    const size_t M = (size_t)B_SZ * S_LEN;  // 4096
    float* cosT  = (float*)alloc((size_t)S_LEN * 64 * 4);
    float* sinT  = (float*)alloc((size_t)S_LEN * 64 * 4);
    float* q_tmp = (float*)alloc(M * 2048 * 4);
    float* k_tmp = (float*)alloc(M * 512 * 4);
    float* v_tmp = (float*)alloc(M * 512 * 4);
    __bf16* qb   = (__bf16*)alloc((size_t)B_SZ * NHEADS * S_LEN * DHEAD * 2);
    __bf16* kb   = (__bf16*)alloc((size_t)B_SZ * NKV * S_LEN * DHEAD * 2);
    __bf16* vt   = (__bf16*)alloc((size_t)B_SZ * NKV * DHEAD * S_LEN * 2);
    __bf16* att  = (__bf16*)alloc(M * DMODEL * 2);
    __bf16* wo_b = (__bf16*)alloc((size_t)DMODEL * DMODEL * 2);
    // aliased bf16 staging buffers (clobbered only AFTER their last GEMM read):
    // vt holds 2,097,152 bf16 elements (4 MB) = exactly wk (1M elems) + wv (1M elems).
    __bf16* qkv_b = att;                       // flash writes att after qkv_proj
    __bf16* wq_b  = qb;                        // postproc writes qb after qkv_proj
    __bf16* wk_b  = vt;                        // v_transpose writes vt after qkv_proj
    __bf16* wv_b  = wk_b + (size_t)NKV * DHEAD * DMODEL;  // element offset, no overlap

    rope_tables_kernel<<<(S_LEN * 64) / 256, 256, 0, stream>>>(cosT, sinT);
    convert_kernel<<<dim3(512, 5), 256, 0, stream>>>(qkv, Wq, Wk, Wv, Wo,
                                                     qkv_b, wq_b, wk_b, wv_b, wo_b);
    qkv_proj_kernel<<<dim3(M / 128, 24), 256, 0, stream>>>(qkv_b, wq_b, wk_b, wv_b,
                                                           q_tmp, k_tmp, v_tmp);
    postproc_kernel<<<dim3(M), 256, 0, stream>>>(q_tmp, k_tmp, qg, kg, cosT, sinT, qb, kb);
    v_transpose_kernel<<<dim3(B_SZ * NKV, S_LEN / 64, DHEAD / 64), 256, 0, stream>>>(v_tmp, vt);
    flash_kernel<<<dim3(B_SZ * NHEADS, 16), 256, 0, stream>>>(qb, kb, vt, att);
    out_proj_kernel<<<dim3(M / 128, DMODEL / 128), 256, 0, stream>>>(att, wo_b, out);
}

// Round 6
// 230.876 us; speedup vs baseline: 2.0284x; 1.0702x over previous
//
#include <hip/hip_runtime.h>

#define S_LEN 2048
#define B_SZ 2
#define DMODEL 2048
#define NHEADS 16
#define NKV 4
#define DHEAD 128
#define SCALE 0.08838834764831845f  // 1/sqrt(128)
#define KVB 32

typedef __bf16 bf16x8 __attribute__((ext_vector_type(8)));
typedef __bf16 bf16x4 __attribute__((ext_vector_type(4)));
typedef float f32x4 __attribute__((ext_vector_type(4)));

#define MFMA(a, b, c) __builtin_amdgcn_mfma_f32_16x16x32_bf16(a, b, c, 0, 0, 0)

__device__ __forceinline__ void gload_lds16(const __bf16* g, __bf16* l) {
    __builtin_amdgcn_global_load_lds(
        (const __attribute__((address_space(1))) unsigned int*)g,
        (__attribute__((address_space(3))) unsigned int*)l, 16, 0, 0);
}

// ---------------------------------------------------------------------------
// RoPE tables: cos/sin [S][64]
// ---------------------------------------------------------------------------
__global__ void rope_tables_kernel(float* __restrict__ cosT, float* __restrict__ sinT) {
    int i = blockIdx.x * 256 + threadIdx.x;       // S*64 entries
    int s = i >> 6, d = i & 63;
    float freq = powf(10000.0f, -(2.0f * (float)d) / 128.0f);
    float ang = (float)s * freq;
    cosT[i] = cosf(ang);
    sinT[i] = sinf(ang);
}

// ---------------------------------------------------------------------------
// fp32 -> bf16 convert, 5 regions (qkv, Wq, Wk, Wv, Wo), 16B stores.
// ---------------------------------------------------------------------------
__global__ __launch_bounds__(256) void convert_kernel(
    const float* __restrict__ s0, const float* __restrict__ s1,
    const float* __restrict__ s2, const float* __restrict__ s3,
    const float* __restrict__ s4,
    __bf16* __restrict__ d0, __bf16* __restrict__ d1, __bf16* __restrict__ d2,
    __bf16* __restrict__ d3, __bf16* __restrict__ d4) {
    const float* s;
    __bf16* d;
    int n8;
    switch (blockIdx.y) {
        case 0: s = s0; d = d0; n8 = (B_SZ * S_LEN * DMODEL) / 8; break;      // qkv
        case 1: s = s1; d = d1; n8 = (DMODEL * DMODEL) / 8; break;            // Wq
        case 2: s = s2; d = d2; n8 = (NKV * DHEAD * DMODEL) / 8; break;       // Wk
        case 3: s = s3; d = d3; n8 = (NKV * DHEAD * DMODEL) / 8; break;       // Wv
        default: s = s4; d = d4; n8 = (DMODEL * DMODEL) / 8; break;           // Wo
    }
    for (int i = blockIdx.x * 256 + threadIdx.x; i < n8; i += 512 * 256) {
        float4 a = ((const float4*)s)[2 * i];
        float4 b = ((const float4*)s)[2 * i + 1];
        bf16x8 o = {(__bf16)a.x, (__bf16)a.y, (__bf16)a.z, (__bf16)a.w,
                    (__bf16)b.x, (__bf16)b.y, (__bf16)b.z, (__bf16)b.w};
        *(bf16x8*)&d[i * 8] = o;
    }
}

// ---------------------------------------------------------------------------
// GEMM (m97 + T3-min 2-phase prefetch): C[m][n] = sum_k A[m][k]*W[n][k].
// 128x128 tile, BK=32, 256 threads = 4 waves (2x2 of 64x64), 16x16x32 MFMA.
// Double-buffered LDS; tile t+1's global_load_lds issued BEFORE tile t's
// compute so the barrier's vmcnt(0) drain lands after a full MFMA phase.
// ---------------------------------------------------------------------------
__device__ __forceinline__ void gemm_bt_bf16(const __bf16* __restrict__ A,
                                             const __bf16* __restrict__ W,
                                             float* __restrict__ C, int ldc,
                                             int bm, int bn, int K) {
    __shared__ alignas(16) __bf16 As[2][128][32];
    __shared__ alignas(16) __bf16 Bs[2][128][32];
    const int tid = threadIdx.x;
    const int lane = tid & 63;
    const int wave = tid >> 6;
    const int lr = lane & 15;        // row-in-16 for A/B frags, col for C
    const int lk = lane >> 4;        // k-chunk id 0..3, row-group for C
    const int wm = (wave >> 1) * 64;
    const int wn = (wave & 1) * 64;
    const int srow = lane >> 2;      // staging: row-in-16 (4 chunks per 64B row)
    const int sc8 = (lane & 3) * 8;  // staging: element offset within row

    auto stage = [&](int bi, int k0) {
#pragma unroll
        for (int i = 0; i < 2; ++i) {
            const int row = i * 64 + wave * 16 + srow;
            gload_lds16(A + (size_t)(bm + row) * K + k0 + sc8,
                        &As[bi][0][0] + i * 2048 + wave * 512);
            gload_lds16(W + (size_t)(bn + row) * K + k0 + sc8,
                        &Bs[bi][0][0] + i * 2048 + wave * 512);
        }
    };

    f32x4 acc[4][4] = {};
    const int NT = K >> 5;

    stage(0, 0);
    __syncthreads();   // tile 0 resident
    for (int t = 0; t < NT; ++t) {
        if (t + 1 < NT) stage((t + 1) & 1, (t + 1) * 32);  // in-flight during MFMA
        const int bi = t & 1;
        bf16x8 af[4], bfr[4];
#pragma unroll
        for (int i = 0; i < 4; ++i) {
            af[i]  = *(const bf16x8*)&As[bi][wm + i * 16 + lr][lk * 8];
            bfr[i] = *(const bf16x8*)&Bs[bi][wn + i * 16 + lr][lk * 8];
        }
#pragma unroll
        for (int mi = 0; mi < 4; ++mi)
#pragma unroll
            for (int ni = 0; ni < 4; ++ni)
                acc[mi][ni] = MFMA(af[mi], bfr[ni], acc[mi][ni]);
        // barrier drains vmcnt (next tile staged) + lgkmcnt (this tile's reads
        // complete on every wave, so next iter may overwrite the other buffer)
        __syncthreads();
    }

#pragma unroll
    for (int mi = 0; mi < 4; ++mi)
#pragma unroll
        for (int ni = 0; ni < 4; ++ni)
#pragma unroll
            for (int r = 0; r < 4; ++r) {
                int row = bm + wm + mi * 16 + lk * 4 + r;
                int col = bn + wn + ni * 16 + lr;
                C[(size_t)row * ldc + col] = acc[mi][ni][r];
            }
}

// grid (M/128, 24): ny 0..15 -> Q, 16..19 -> K, 20..23 -> V
__global__ __launch_bounds__(256) void qkv_proj_kernel(
    const __bf16* __restrict__ qkvb, const __bf16* __restrict__ Wq,
    const __bf16* __restrict__ Wk, const __bf16* __restrict__ Wv,
    float* __restrict__ q_tmp, float* __restrict__ k_tmp, float* __restrict__ v_tmp) {
    int bm = blockIdx.x * 128;
    int ny = blockIdx.y;
    const __bf16* W;
    float* C;
    int ldc, bn;
    if (ny < 16)      { W = Wq; C = q_tmp; ldc = 2048; bn = ny * 128; }
    else if (ny < 20) { W = Wk; C = k_tmp; ldc = 512;  bn = (ny - 16) * 128; }
    else              { W = Wv; C = v_tmp; ldc = 512;  bn = (ny - 20) * 128; }
    gemm_bt_bf16(qkvb, W, C, ldc, bm, bn, 2048);
}

__global__ __launch_bounds__(256) void out_proj_kernel(
    const __bf16* __restrict__ att, const __bf16* __restrict__ Wo,
    float* __restrict__ out) {
    gemm_bt_bf16(att, Wo, out, 2048, blockIdx.x * 128, blockIdx.y * 128, 2048);
}

// ---------------------------------------------------------------------------
// RMSNorm + RoPE + bf16 + transpose for Q,K.  grid (B*S), 256 threads.
// qb: [B,H,S,Dh] (pre-scaled by 1/sqrt(Dh))  kb: [B,KV,S,Dh]
// ---------------------------------------------------------------------------
__global__ __launch_bounds__(256) void postproc_kernel(
    const float* __restrict__ q_tmp, const float* __restrict__ k_tmp,
    const float* __restrict__ qg, const float* __restrict__ kg,
    const float* __restrict__ cosT, const float* __restrict__ sinT,
    __bf16* __restrict__ qb, __bf16* __restrict__ kb) {
    int bs = blockIdx.x;
    int b = bs >> 11, s = bs & 2047;
    int wave = threadIdx.x >> 6, lane = threadIdx.x & 63;
    float c  = cosT[s * 64 + lane];
    float sn = sinT[s * 64 + lane];
    float g1q = qg[lane], g2q = qg[lane + 64];
    float g1k = kg[lane], g2k = kg[lane + 64];

    for (int h = wave; h < NHEADS; h += 4) {
        const float* row = q_tmp + (size_t)bs * 2048 + h * 128;
        float x1 = row[lane], x2 = row[lane + 64];
        float ss = x1 * x1 + x2 * x2;
#pragma unroll
        for (int m = 1; m < 64; m <<= 1) ss += __shfl_xor(ss, m);
        float rs = rsqrtf(ss * (1.0f / 128.0f) + 1e-6f);
        float n1 = x1 * rs * g1q, n2 = x2 * rs * g2q;
        // fold the attention score scale into q
        float y1 = (n1 * c - n2 * sn) * SCALE;
        float y2 = (n2 * c + n1 * sn) * SCALE;
        __bf16* orow = qb + (((size_t)(b * NHEADS + h)) * S_LEN + s) * DHEAD;
        orow[lane] = (__bf16)y1;
        orow[lane + 64] = (__bf16)y2;
    }
    int h = wave;
    if (h < NKV) {
        const float* row = k_tmp + (size_t)bs * 512 + h * 128;
        float x1 = row[lane], x2 = row[lane + 64];
        float ss = x1 * x1 + x2 * x2;
#pragma unroll
        for (int m = 1; m < 64; m <<= 1) ss += __shfl_xor(ss, m);
        float rs = rsqrtf(ss * (1.0f / 128.0f) + 1e-6f);
        float n1 = x1 * rs * g1k, n2 = x2 * rs * g2k;
        float y1 = n1 * c - n2 * sn;
        float y2 = n2 * c + n1 * sn;
        __bf16* orow = kb + (((size_t)(b * NKV + h)) * S_LEN + s) * DHEAD;
        orow[lane] = (__bf16)y1;
        orow[lane + 64] = (__bf16)y2;
    }
}

// ---------------------------------------------------------------------------
// V transpose: v_tmp fp32 [B*S][512] -> vt bf16 [B,KV,Dh,S]
// ---------------------------------------------------------------------------
__global__ __launch_bounds__(256) void v_transpose_kernel(
    const float* __restrict__ v_tmp, __bf16* __restrict__ vt) {
    int bkv = blockIdx.x;
    int b = bkv >> 2, kvh = bkv & 3;
    int s0 = blockIdx.y * 64, d0 = blockIdx.z * 64;
    __shared__ float tile[64][65];
#pragma unroll
    for (int i = 0; i < 16; ++i) {
        int idx = threadIdx.x + i * 256;
        int r = idx >> 6, cc = idx & 63;
        tile[r][cc] = v_tmp[((size_t)(b * S_LEN) + s0 + r) * 512 + kvh * 128 + d0 + cc];
    }
    __syncthreads();
#pragma unroll
    for (int i = 0; i < 16; ++i) {
        int idx = threadIdx.x + i * 256;
        int r = idx >> 6, cc = idx & 63;   // r = d-local, cc = s-local
        vt[((size_t)bkv * DHEAD + d0 + r) * S_LEN + s0 + cc] = (__bf16)tile[cc][r];
    }
}

// ---------------------------------------------------------------------------
// Causal flash attention with block-shared double-buffered K/V LDS staging.
// grid (B*H, 16), 256 threads = 4 waves.
// ---------------------------------------------------------------------------
__global__ __launch_bounds__(256, 2) void flash_kernel(
    const __bf16* __restrict__ qb, const __bf16* __restrict__ kb,
    const __bf16* __restrict__ vt, __bf16* __restrict__ att) {
    __shared__ alignas(16) __bf16 K_lds[2][32 * 128];   // 8KB each
    __shared__ alignas(16) __bf16 V_lds[2][128 * 32];   // 8KB each
    __shared__ alignas(16) __bf16 p_lds[4][16][40];

    const int bh = blockIdx.x;
    const int b = bh >> 4, h = bh & 15, kv = h >> 2;
    const int j = blockIdx.y;  // 0..15
    const int lane = threadIdx.x & 63, wave = threadIdx.x >> 6;
    const int lr = lane & 15, lk = lane >> 4;

    const int qloB = j * 64 + wave * 16;
    const int qhiB = (31 - j) * 64 + wave * 16;
    const int ntL  = ((qloB + 15) >> 5) + 1;   // per-wave low-frag tiles
    const int ntHw = ((qhiB + 15) >> 5) + 1;   // per-wave high-frag tiles
    const int ntH  = 64 - 2 * j;               // block-uniform staged tiles

    const __bf16* Qp = qb + ((size_t)(b * NHEADS + h)) * S_LEN * DHEAD;
    const __bf16* Kp = kb + ((size_t)(b * NKV + kv)) * S_LEN * DHEAD;
    const __bf16* Vt = vt + ((size_t)(b * NKV + kv)) * DHEAD * S_LEN;

    bf16x8 qlo[4], qhi[4];
#pragma unroll
    for (int f = 0; f < 4; ++f) {
        qlo[f] = *(const bf16x8*)&Qp[(size_t)(qloB + lr) * DHEAD + f * 32 + lk * 8];
        qhi[f] = *(const bf16x8*)&Qp[(size_t)(qhiB + lr) * DHEAD + f * 32 + lk * 8];
    }

    // staging lane constants (inverse-swizzled global source)
    const int c0 = 2 * wave;
    const int l4 = lane >> 4, l15 = lane & 15;
    const int l2 = lane >> 2, l3 = lane & 3;
    const int vcol = ((l3 ^ (l2 & 3)) << 3);

    auto stage = [&](int bufi, int t) {
        const int k0s = t * KVB;
#pragma unroll
        for (int i = 0; i < 2; ++i) {
            const int c = c0 + i;
            const int rK = c * 4 + l4;
            const int kcol = ((l15 ^ (rK & 7)) << 3);
            gload_lds16(Kp + (size_t)(k0s + rK) * DHEAD + kcol, &K_lds[bufi][c * 512]);
            const int rV = c * 16 + l2;
            gload_lds16(Vt + (size_t)rV * S_LEN + k0s + vcol, &V_lds[bufi][c * 512]);
        }
    };

    f32x4 accL[8] = {}, accH[8] = {};
    float lsumL[4] = {0.f, 0.f, 0.f, 0.f}, lsumH[4] = {0.f, 0.f, 0.f, 0.f};
    const int swzK = (lr & 7) << 4;
    const int swzV = (lr & 3) << 4;

    auto frag_step = [&](const bf16x8 (&qf)[4], int qbase, f32x4 (&acc)[8],
                         float (&lsum)[4], const bf16x8 (&kf)[8],
                         const bf16x8 (&vf)[8], int k0) {
        f32x4 sc[2] = {};
#pragma unroll
        for (int kk = 0; kk < 2; ++kk)
#pragma unroll
            for (int f = 0; f < 4; ++f)
                sc[kk] = MFMA(qf[f], kf[kk * 4 + f], sc[kk]);
        // prior p_lds reads (this wave) must complete before overwrite
        asm volatile("s_waitcnt lgkmcnt(0)" ::: "memory");
#pragma unroll
        for (int r = 0; r < 4; ++r) {
            const int qr = qbase + lk * 4 + r;
            float s0 = sc[0][r], s1 = sc[1][r];
            if (k0 + lr > qr) s0 = -1e30f;
            if (k0 + 16 + lr > qr) s1 = -1e30f;
            float p0 = __expf(s0), p1 = __expf(s1);
            lsum[r] += p0 + p1;
            p_lds[wave][lk * 4 + r][lr] = (__bf16)p0;
            p_lds[wave][lk * 4 + r][lr + 16] = (__bf16)p1;
        }
        asm volatile("s_waitcnt lgkmcnt(0)" ::: "memory");
        bf16x8 pf = *(const bf16x8*)&p_lds[wave][lr][lk * 8];
#pragma unroll
        for (int nf = 0; nf < 8; ++nf)
            acc[nf] = MFMA(pf, vf[nf], acc[nf]);
    };

    int cur = 0;
    stage(0, 0);
    __syncthreads();   // drains stage vmcnt before first use
    for (int t = 0; t < ntH; ++t) {
        if (t + 1 < ntH) stage(cur ^ 1, t + 1);
        const int k0 = t * KVB;
        bf16x8 kf[8], vf[8];
#pragma unroll
        for (int kk = 0; kk < 2; ++kk)
#pragma unroll
            for (int f = 0; f < 4; ++f) {
                const int cb = (f * 64 + lk * 16) ^ swzK;
                kf[kk * 4 + f] =
                    *(const bf16x8*)((const char*)&K_lds[cur][(kk * 16 + lr) * 128] + cb);
            }
#pragma unroll
        for (int nf = 0; nf < 8; ++nf) {
            const int cb = (lk * 16) ^ swzV;
            vf[nf] = *(const bf16x8*)((const char*)&V_lds[cur][(nf * 16 + lr) * 32] + cb);
        }
        if (t < ntHw) frag_step(qhi, qhiB, accH, lsumH, kf, vf, k0);
        if (t < ntL)  frag_step(qlo, qloB, accL, lsumL, kf, vf, k0);
        __syncthreads();   // all waves done with buf[cur]; next stage reuses it
        cur ^= 1;
    }

    // ---- cross-lane row sums
#pragma unroll
    for (int r = 0; r < 4; ++r) {
#pragma unroll
        for (int m = 1; m < 16; m <<= 1) {
            lsumL[r] += __shfl_xor(lsumL[r], m);
            lsumH[r] += __shfl_xor(lsumH[r], m);
        }
    }
    // ---- normalize + store (att row-major [B*S][2048])
#pragma unroll
    for (int nf = 0; nf < 8; ++nf)
#pragma unroll
        for (int r = 0; r < 4; ++r) {
            int qrL = qloB + lk * 4 + r;
            int qrH = qhiB + lk * 4 + r;
            att[((size_t)(b * S_LEN) + qrL) * DMODEL + h * DHEAD + nf * 16 + lr] =
                (__bf16)(accL[nf][r] / lsumL[r]);
            att[((size_t)(b * S_LEN) + qrH) * DMODEL + h * DHEAD + nf * 16 + lr] =
                (__bf16)(accH[nf][r] / lsumH[r]);
        }
}

// ---------------------------------------------------------------------------
extern "C" void kernel_launch(void* const* d_in, const int* in_sizes, int n_in,
                              void* d_out, int out_size, void* d_ws, size_t ws_size,
                              hipStream_t stream) {
    const float* qkv = (const float*)d_in[0];
    const float* Wq  = (const float*)d_in[1];
    const float* Wk  = (const float*)d_in[2];
    const float* Wv  = (const float*)d_in[3];
    const float* Wo  = (const float*)d_in[4];
    const float* qg  = (const float*)d_in[5];
    const float* kg  = (const float*)d_in[6];
    float* out = (float*)d_out;

    size_t off = 0;
    char* wsb = (char*)d_ws;
    auto alloc = [&](size_t n) {
        char* p = wsb + off;
        off += (n + 255) & ~(size_t)255;
        return (void*)p;
    };
    const size_t M = (size_t)B_SZ * S_LEN;  // 4096
    float* cosT  = (float*)alloc((size_t)S_LEN * 64 * 4);
    float* sinT  = (float*)alloc((size_t)S_LEN * 64 * 4);
    float* q_tmp = (float*)alloc(M * 2048 * 4);
    float* k_tmp = (float*)alloc(M * 512 * 4);
    float* v_tmp = (float*)alloc(M * 512 * 4);
    __bf16* qb   = (__bf16*)alloc((size_t)B_SZ * NHEADS * S_LEN * DHEAD * 2);
    __bf16* kb   = (__bf16*)alloc((size_t)B_SZ * NKV * S_LEN * DHEAD * 2);
    __bf16* vt   = (__bf16*)alloc((size_t)B_SZ * NKV * DHEAD * S_LEN * 2);
    __bf16* att  = (__bf16*)alloc(M * DMODEL * 2);
    __bf16* wo_b = (__bf16*)alloc((size_t)DMODEL * DMODEL * 2);
    // aliased bf16 staging buffers (clobbered only AFTER their last GEMM read):
    // vt holds 2,097,152 bf16 elements (4 MB) = exactly wk (1M elems) + wv (1M elems).
    __bf16* qkv_b = att;                       // flash writes att after qkv_proj
    __bf16* wq_b  = qb;                        // postproc writes qb after qkv_proj
    __bf16* wk_b  = vt;                        // v_transpose writes vt after qkv_proj
    __bf16* wv_b  = wk_b + (size_t)NKV * DHEAD * DMODEL;  // element offset, no overlap

    rope_tables_kernel<<<(S_LEN * 64) / 256, 256, 0, stream>>>(cosT, sinT);
    convert_kernel<<<dim3(512, 5), 256, 0, stream>>>(qkv, Wq, Wk, Wv, Wo,
                                                     qkv_b, wq_b, wk_b, wv_b, wo_b);
    qkv_proj_kernel<<<dim3(M / 128, 24), 256, 0, stream>>>(qkv_b, wq_b, wk_b, wv_b,
                                                           q_tmp, k_tmp, v_tmp);
    postproc_kernel<<<dim3(M), 256, 0, stream>>>(q_tmp, k_tmp, qg, kg, cosT, sinT, qb, kb);
    v_transpose_kernel<<<dim3(B_SZ * NKV, S_LEN / 64, DHEAD / 64), 256, 0, stream>>>(v_tmp, vt);
    flash_kernel<<<dim3(B_SZ * NHEADS, 16), 256, 0, stream>>>(qb, kb, vt, att);
    out_proj_kernel<<<dim3(M / 128, DMODEL / 128), 256, 0, stream>>>(att, wo_b, out);
}